// Round 6
// baseline (791.444 us; speedup 1.0000x reference)
//
#include <hip/hip_runtime.h>
#include <stdint.h>

#define VOCAB 28996
#define EMBED 512
#define NROWS 8192
#define VPAD  29056  /* 227 * 128 */
#define LOG2E 1.4426950408889634f
#define WSCALE 16.0f
#define INV_WSCALE_L2E (LOG2E / 16.0f)

typedef __attribute__((ext_vector_type(4)))  int   i32x4;
typedef __attribute__((ext_vector_type(8)))  int   i32x8;
typedef __attribute__((ext_vector_type(16))) float f32x16;

__device__ __forceinline__ void gload_lds16(const void* g, void* l) {
  __builtin_amdgcn_global_load_lds(
      (__attribute__((address_space(1))) const void*)g,
      (__attribute__((address_space(3))) void*)l, 16, 0, 0);
}

// pack 4 floats -> 4 x fp8 e4m3 (OCP, RNE, saturating) in one i32
__device__ __forceinline__ int pk_fp8x4(float a, float b, float c, float d) {
  int r = __builtin_amdgcn_cvt_pk_fp8_f32(a, b, 0, false);
  r = __builtin_amdgcn_cvt_pk_fp8_f32(c, d, r, true);
  return r;
}

// ---- fused prep (IDENTICAL to the harness-verified round-0 kernel) ----
// blocks [0,7264): W   (VPAD*512/8/256 = 7264)
// blocks [7264,9312): x (8192*512/8/256 = 2048)
// blocks [9312,11360): py (1 wave/row, 4 rows/block)
// blocks [11360,11392): zero sg
__global__ void __launch_bounds__(256)
prep_kernel(const float* __restrict__ x, const float* __restrict__ W,
            const float* __restrict__ b, const int* __restrict__ y,
            int* __restrict__ xb, int* __restrict__ wb,
            float* __restrict__ py, float* __restrict__ sg) {
  const int bid = blockIdx.x;
  if (bid < 7264) {                        // ---- cvt W*16 -> fp8 ----
    int i = (bid * 256 + threadIdx.x) * 8; // float index; VK multiple of 8
    const int VK = VOCAB * EMBED;
    int2 o;
    if (i < VK) {
      float4 v0 = *(const float4*)(W + i);
      float4 v1 = *(const float4*)(W + i + 4);
      o.x = pk_fp8x4(v0.x * WSCALE, v0.y * WSCALE, v0.z * WSCALE, v0.w * WSCALE);
      o.y = pk_fp8x4(v1.x * WSCALE, v1.y * WSCALE, v1.z * WSCALE, v1.w * WSCALE);
    } else { o.x = 0; o.y = 0; }
    *(int2*)(wb + i / 4) = o;
  } else if (bid < 9312) {                 // ---- cvt x -> fp8 ----
    int i = ((bid - 7264) * 256 + threadIdx.x) * 8;
    float4 v0 = *(const float4*)(x + i);
    float4 v1 = *(const float4*)(x + i + 4);
    int2 o;
    o.x = pk_fp8x4(v0.x, v0.y, v0.z, v0.w);
    o.y = pk_fp8x4(v1.x, v1.y, v1.z, v1.w);
    *(int2*)(xb + i / 4) = o;
  } else if (bid < 11360) {                // ---- py: e^{x.W[y]+b[y]}, fp32 exact ----
    const int row  = ((bid - 9312) * 256 + threadIdx.x) >> 6;
    const int lane = threadIdx.x & 63;
    const int yr = y[row];
    const float4* xr = (const float4*)(x + (size_t)row * EMBED);
    const float4* wr = (const float4*)(W + (size_t)yr * EMBED);
    float d = 0.f;
#pragma unroll
    for (int t = 0; t < 2; ++t) {
      float4 a = xr[lane * 2 + t], c = wr[lane * 2 + t];
      d += a.x * c.x + a.y * c.y + a.z * c.z + a.w * c.w;
    }
#pragma unroll
    for (int m = 1; m < 64; m <<= 1) d += __shfl_xor(d, m);
    if (lane == 0) py[row] = __expf(d + b[yr]);
  } else {                                 // ---- zero sg ----
    int i = (bid - 11360) * 256 + threadIdx.x;
    sg[i] = 0.f;
  }
}

// ---- fused GEMM (16*logits = x . (16W)^T, MX-fp8 32x32x64) + row-sum exp ----
// Round-6 geometry: tile 128x256 (BM=128 rows, BN=256 cols), BK=128,
// SINGLE buffer, r0's proven 2-barrier schedule (stage; sync; compute; sync),
// 4 waves each owning 128x64 = 4(mi) x 2(ni) of 32x32 — i.e. r2/r3's
// proven-correct wave-level compute inside r0's proven-fast block schedule.
// Why: r0's LDS-pipe is the top pipe (~69% busy: 256 b128-reads + 4-way
// conflict + staging writes per block). Wave tile 128x64 cuts fragment
// reads/MFMA from 2.0 to 1.5 (reads ~ 2(a+b), mfma ~ a*b; a=4,b=2), and
// halves the per-chip epilogue cost (7296 blocks vs 14528).
// LDS 16K(A)+32K(B) = 48 KiB -> 3 blocks/CU (launch_bounds(256,3) caps
// regs at ~170; acc 128 + bq 16 + af 8 + addr fits).
// LDS layout = r0's proven one: row = 128 B, 16B-chunk XOR swizzle with
// 3-bit key (chunk J of row R at R*128 + ((J^(R&7))*16)) -> 4-way read
// conflict floor (+4cy/read), staging linear for global_load_lds with
// pre-swizzled global source.
// Tail (grid.y=114 covers 29184 > VPAD): clamp B staging row to VPAD-8
// (re-reads finite fp8; saturating cvt emits no NaN encodings) and
// bias=-1e30 for col>=VOCAB zeroes their exp contribution. (Proven in r2/r3.)
__global__ void __launch_bounds__(256, 3)
gemm_stats_kernel(const uint8_t* __restrict__ xb, const uint8_t* __restrict__ wb,
                  const float* __restrict__ bias, float* __restrict__ sg) {
  __shared__ uint8_t lA[128 * 128];   // 16 KiB
  __shared__ uint8_t lB[256 * 128];   // 32 KiB

  const int tid  = threadIdx.x;
  const int lane = tid & 63;
  const int w    = tid >> 6;       // wave 0..3
  const int l31  = lane & 31;
  const int h    = lane >> 5;      // k-half for 32x32 operands
  const int kx   = lane & 7;       // swizzle key (fragment row & 7 == lane & 7)
  const int wc   = w * 64;         // wave col offset in tile (rows: all 128)
  const int rowBase = blockIdx.x * 128;  // x rows     (grid.x = 64)
  const int colBase = blockIdx.y * 256;  // vocab cols (grid.y = 114)

  const int srow = lane >> 3;                 // 0..7 (row within 8-row chunk)
  const int skel = (kx ^ srow) * 16;          // swizzled byte offset in row

  f32x16 acc[4][2];
#pragma unroll
  for (int i = 0; i < 4; ++i)
#pragma unroll
    for (int j = 0; j < 2; ++j)
#pragma unroll
      for (int r = 0; r < 16; ++r) acc[i][j][r] = 0.f;

  // staging: chunk = 8 rows x 128 B; lane covers global row c*8+srow at
  // global 16B slot (kx^srow) -> LDS linear lane*16 within the chunk.
  // A: 16 chunks (4/wave); B: 32 chunks (8/wave).
  auto stage = [&](int k0) {
#pragma unroll
    for (int t = 0; t < 4; ++t) {
      const int c = w * 4 + t;               // A chunk 0..15
      gload_lds16(xb + (size_t)(rowBase + c * 8 + srow) * EMBED + k0 + skel,
                  &lA[c * 1024]);
    }
#pragma unroll
    for (int t = 0; t < 8; ++t) {
      const int c = w * 8 + t;               // B chunk 0..31
      int br = colBase + c * 8;
      if (br > VPAD - 8) br = VPAD - 8;      // tail clamp (see header comment)
      gload_lds16(wb + (size_t)(br + srow) * EMBED + k0 + skel,
                  &lB[c * 1024]);
    }
  };

  const int aBase = l31 * 128;               // + mi*32*128
  const int bBase = (wc + l31) * 128;        // + ni*32*128

#pragma unroll
  for (int kt = 0; kt < 4; ++kt) {
    stage(kt * 128);
    __syncthreads();                         // vmcnt(0)+lgkmcnt(0)+barrier
#pragma unroll
    for (int kk = 0; kk < 2; ++kk) {
      const int c0 = ((kk * 4 + h * 2) ^ kx) << 4;
      const int c1 = c0 ^ 16;
      i32x8 bq[2];
#pragma unroll
      for (int ni = 0; ni < 2; ++ni) {
        const uint8_t* bp = &lB[bBase + ni * 32 * 128];
        i32x4 lo = *(const i32x4*)(bp + c0);
        i32x4 hi = *(const i32x4*)(bp + c1);
        bq[ni] = __builtin_shufflevector(lo, hi, 0, 1, 2, 3, 4, 5, 6, 7);
      }
#pragma unroll
      for (int mi = 0; mi < 4; ++mi) {
        const uint8_t* ap = &lA[aBase + mi * 32 * 128];
        i32x4 lo = *(const i32x4*)(ap + c0);
        i32x4 hi = *(const i32x4*)(ap + c1);
        i32x8 af = __builtin_shufflevector(lo, hi, 0, 1, 2, 3, 4, 5, 6, 7);
        acc[mi][0] = __builtin_amdgcn_mfma_scale_f32_32x32x64_f8f6f4(
            af, bq[0], acc[mi][0], 0, 0, 0, 0x7F7F7F7F, 0, 0x7F7F7F7F);
        acc[mi][1] = __builtin_amdgcn_mfma_scale_f32_32x32x64_f8f6f4(
            af, bq[1], acc[mi][1], 0, 0, 0, 0x7F7F7F7F, 0, 0x7F7F7F7F);
      }
    }
    __syncthreads();                         // protect buffer reuse (single buf)
  }

  // ---- epilogue: s_row += sum_j exp(acc/16 + bias) ----
  // 32x32 C/D layout (m74/m101): col = lane&31, row = (reg&3)+8*(reg>>2)+4*h
  float bvl[2];
#pragma unroll
  for (int ni = 0; ni < 2; ++ni) {
    const int col = colBase + wc + ni * 32 + l31;
    bvl[ni] = (col < VOCAB) ? bias[col] * LOG2E : -1e30f;
  }

#pragma unroll
  for (int p = 0; p < 2; ++p) {            // p: 64-row half of the wave tile
    float sp[32];  // v = q*16 + reg, mi = p*2 + q
#pragma unroll
    for (int q = 0; q < 2; ++q)
#pragma unroll
      for (int r = 0; r < 16; ++r)
        sp[q * 16 + r] =
            exp2f(fmaf(acc[p * 2 + q][0][r], INV_WSCALE_L2E, bvl[0])) +
            exp2f(fmaf(acc[p * 2 + q][1][r], INV_WSCALE_L2E, bvl[1]));

    // stacking reduction over the 32 cols (xor 1..16 stays within the h-half);
    // ends with lane holding the full col-sum for value index v == (lane&31).
    float t1[16];
#pragma unroll
    for (int u = 0; u < 16; ++u) {
      float a = sp[2 * u]     + __shfl_xor(sp[2 * u],     1);
      float b = sp[2 * u + 1] + __shfl_xor(sp[2 * u + 1], 1);
      t1[u] = (l31 & 1) ? b : a;
    }
    float t2[8];
#pragma unroll
    for (int u = 0; u < 8; ++u) {
      float a = t1[2 * u]     + __shfl_xor(t1[2 * u],     2);
      float b = t1[2 * u + 1] + __shfl_xor(t1[2 * u + 1], 2);
      t2[u] = (l31 & 2) ? b : a;
    }
    float t3[4];
#pragma unroll
    for (int u = 0; u < 4; ++u) {
      float a = t2[2 * u]     + __shfl_xor(t2[2 * u],     4);
      float b = t2[2 * u + 1] + __shfl_xor(t2[2 * u + 1], 4);
      t3[u] = (l31 & 4) ? b : a;
    }
    float t4[2];
#pragma unroll
    for (int u = 0; u < 2; ++u) {
      float a = t3[2 * u]     + __shfl_xor(t3[2 * u],     8);
      float b = t3[2 * u + 1] + __shfl_xor(t3[2 * u + 1], 8);
      t4[u] = (l31 & 8) ? b : a;
    }
    {
      float a = t4[0] + __shfl_xor(t4[0], 16);
      float b = t4[1] + __shfl_xor(t4[1], 16);
      float ssum = (l31 & 16) ? b : a;
      const int v = l31;                 // q = v>>4, reg = v&15
      const int row = rowBase + p * 64 + (v >> 4) * 32 +
                      (v & 3) + 8 * ((v & 15) >> 2) + 4 * h;
      atomicAdd(&sg[row], ssum);
    }
  }
}

// ---- final: loss = log(V+1) - mean(py/s)  (q-term ~7e-10, dropped) ----
__global__ void finalize_kernel(const float* __restrict__ sg, const float* __restrict__ py,
                                float* __restrict__ out) {
  __shared__ float red[256];
  float a = 0.f;
  for (int i = threadIdx.x; i < NROWS; i += 256)
    a += py[i] / sg[i];
  red[threadIdx.x] = a;
  __syncthreads();
  for (int st = 128; st > 0; st >>= 1) {
    if (threadIdx.x < st) red[threadIdx.x] += red[threadIdx.x + st];
    __syncthreads();
  }
  if (threadIdx.x == 0)
    out[0] = logf((float)(VOCAB + 1)) - red[0] * (1.f / (float)NROWS);
}

extern "C" void kernel_launch(void* const* d_in, const int* in_sizes, int n_in,
                              void* d_out, int out_size, void* d_ws, size_t ws_size,
                              hipStream_t stream) {
  const float* x = (const float*)d_in[0];
  const int*   y = (const int*)d_in[1];
  const float* W = (const float*)d_in[2];
  const float* b = (const float*)d_in[3];

  char* ws = (char*)d_ws;
  uint8_t* xb = (uint8_t*)ws;                             // 4,194,304 B
  uint8_t* wb = (uint8_t*)(ws + 4194304);                 // 14,876,672 B
  float*   sg = (float*)(ws + 4194304 + 14876672);        // 32 KiB
  float*   py = sg + NROWS;                               // 32 KiB

  prep_kernel<<<11392, 256, 0, stream>>>(x, W, b, y, (int*)xb, (int*)wb, py, sg);
  gemm_stats_kernel<<<dim3(64, 114), 256, 0, stream>>>(xb, wb, b, sg);
  finalize_kernel<<<1, 256, 0, stream>>>(sg, py, (float*)d_out);
}

// Round 7
// 274.948 us; speedup vs baseline: 2.8785x; 2.8785x over previous
//
#include <hip/hip_runtime.h>
#include <stdint.h>

#define VOCAB 28996
#define EMBED 512
#define NROWS 8192
#define VPAD  29056  /* 227 * 128 */
#define LOG2E 1.4426950408889634f
#define WSCALE 16.0f
#define INV_WSCALE_L2E (LOG2E / 16.0f)

typedef __attribute__((ext_vector_type(4)))  int   i32x4;
typedef __attribute__((ext_vector_type(8)))  int   i32x8;
typedef __attribute__((ext_vector_type(16))) float f32x16;

__device__ __forceinline__ void gload_lds16(const void* g, void* l) {
  __builtin_amdgcn_global_load_lds(
      (__attribute__((address_space(1))) const void*)g,
      (__attribute__((address_space(3))) void*)l, 16, 0, 0);
}

// pack 4 floats -> 4 x fp8 e4m3 (OCP, RNE, saturating) in one i32
__device__ __forceinline__ int pk_fp8x4(float a, float b, float c, float d) {
  int r = __builtin_amdgcn_cvt_pk_fp8_f32(a, b, 0, false);
  r = __builtin_amdgcn_cvt_pk_fp8_f32(c, d, r, true);
  return r;
}

// ---- fused prep (IDENTICAL to the harness-verified round-0 kernel) ----
// blocks [0,7264): W   (VPAD*512/8/256 = 7264)
// blocks [7264,9312): x (8192*512/8/256 = 2048)
// blocks [9312,11360): py (1 wave/row, 4 rows/block)
// blocks [11360,11392): zero sg
__global__ void __launch_bounds__(256)
prep_kernel(const float* __restrict__ x, const float* __restrict__ W,
            const float* __restrict__ b, const int* __restrict__ y,
            int* __restrict__ xb, int* __restrict__ wb,
            float* __restrict__ py, float* __restrict__ sg) {
  const int bid = blockIdx.x;
  if (bid < 7264) {                        // ---- cvt W*16 -> fp8 ----
    int i = (bid * 256 + threadIdx.x) * 8; // float index; VK multiple of 8
    const int VK = VOCAB * EMBED;
    int2 o;
    if (i < VK) {
      float4 v0 = *(const float4*)(W + i);
      float4 v1 = *(const float4*)(W + i + 4);
      o.x = pk_fp8x4(v0.x * WSCALE, v0.y * WSCALE, v0.z * WSCALE, v0.w * WSCALE);
      o.y = pk_fp8x4(v1.x * WSCALE, v1.y * WSCALE, v1.z * WSCALE, v1.w * WSCALE);
    } else { o.x = 0; o.y = 0; }
    *(int2*)(wb + i / 4) = o;
  } else if (bid < 9312) {                 // ---- cvt x -> fp8 ----
    int i = ((bid - 7264) * 256 + threadIdx.x) * 8;
    float4 v0 = *(const float4*)(x + i);
    float4 v1 = *(const float4*)(x + i + 4);
    int2 o;
    o.x = pk_fp8x4(v0.x, v0.y, v0.z, v0.w);
    o.y = pk_fp8x4(v1.x, v1.y, v1.z, v1.w);
    *(int2*)(xb + i / 4) = o;
  } else if (bid < 11360) {                // ---- py: e^{x.W[y]+b[y]}, fp32 exact ----
    const int row  = ((bid - 9312) * 256 + threadIdx.x) >> 6;
    const int lane = threadIdx.x & 63;
    const int yr = y[row];
    const float4* xr = (const float4*)(x + (size_t)row * EMBED);
    const float4* wr = (const float4*)(W + (size_t)yr * EMBED);
    float d = 0.f;
#pragma unroll
    for (int t = 0; t < 2; ++t) {
      float4 a = xr[lane * 2 + t], c = wr[lane * 2 + t];
      d += a.x * c.x + a.y * c.y + a.z * c.z + a.w * c.w;
    }
#pragma unroll
    for (int m = 1; m < 64; m <<= 1) d += __shfl_xor(d, m);
    if (lane == 0) py[row] = __expf(d + b[yr]);
  } else {                                 // ---- zero sg ----
    int i = (bid - 11360) * 256 + threadIdx.x;
    sg[i] = 0.f;
  }
}

// ---- fused GEMM (16*logits = x . (16W)^T, MX-fp8 32x32x64) + row-sum exp ----
// Round-7 = round-6 geometry with the REGISTER BUDGET FIXED.
// r6's launch_bounds(256,3) capped the unified reg file at ~168/wave, but
// this geometry needs acc(128 AGPR) + ~85 VGPR ≈ 213 — the accumulator
// spilled to scratch (WRITE_SIZE 14.5MB -> 2.23GB, HBM-bound, MfmaUtil 7%).
// launch_bounds(256,2) -> budget 256/wave: fits with headroom (precedent:
// r2/r3 at (512,2) ran 108 VGPR + 128 AGPR, zero spill).
// Geometry: tile 128x256, BK=128, single buffer, r0's 2-barrier schedule
// (stage; sync; compute; sync), 4 waves each owning 128x64 = 4(mi) x 2(ni)
// of 32x32. Wave tile 128x64 cuts LDS fragment reads/MFMA from r0's 2.0 to
// 1.5, and halves the block count (7296 vs 14528) -> half the epilogue work.
// LDS 16K(A)+32K(B) = 48 KiB; occupancy 2 blocks/CU (VGPR-limited).
// LDS layout = r0's proven one: row = 128 B, 16B-chunk XOR swizzle with
// 3-bit key (chunk J of row R at R*128 + ((J^(R&7))*16)) -> 4-way read
// conflict floor (+4cy/read), staging linear for global_load_lds with
// pre-swizzled global source.
// Tail (grid.y=114 covers 29184 > VPAD): clamp B staging row to VPAD-8
// (re-reads finite fp8; saturating cvt emits no NaN encodings) and
// bias=-1e30 for col>=VOCAB zeroes their exp contribution. (Proven r2/r3/r6.)
__global__ void __launch_bounds__(256, 2)
gemm_stats_kernel(const uint8_t* __restrict__ xb, const uint8_t* __restrict__ wb,
                  const float* __restrict__ bias, float* __restrict__ sg) {
  __shared__ uint8_t lA[128 * 128];   // 16 KiB
  __shared__ uint8_t lB[256 * 128];   // 32 KiB

  const int tid  = threadIdx.x;
  const int lane = tid & 63;
  const int w    = tid >> 6;       // wave 0..3
  const int l31  = lane & 31;
  const int h    = lane >> 5;      // k-half for 32x32 operands
  const int kx   = lane & 7;       // swizzle key (fragment row & 7 == lane & 7)
  const int wc   = w * 64;         // wave col offset in tile (rows: all 128)
  const int rowBase = blockIdx.x * 128;  // x rows     (grid.x = 64)
  const int colBase = blockIdx.y * 256;  // vocab cols (grid.y = 114)

  const int srow = lane >> 3;                 // 0..7 (row within 8-row chunk)
  const int skel = (kx ^ srow) * 16;          // swizzled byte offset in row

  f32x16 acc[4][2];
#pragma unroll
  for (int i = 0; i < 4; ++i)
#pragma unroll
    for (int j = 0; j < 2; ++j)
#pragma unroll
      for (int r = 0; r < 16; ++r) acc[i][j][r] = 0.f;

  // staging: chunk = 8 rows x 128 B; lane covers global row c*8+srow at
  // global 16B slot (kx^srow) -> LDS linear lane*16 within the chunk.
  // A: 16 chunks (4/wave); B: 32 chunks (8/wave).
  auto stage = [&](int k0) {
#pragma unroll
    for (int t = 0; t < 4; ++t) {
      const int c = w * 4 + t;               // A chunk 0..15
      gload_lds16(xb + (size_t)(rowBase + c * 8 + srow) * EMBED + k0 + skel,
                  &lA[c * 1024]);
    }
#pragma unroll
    for (int t = 0; t < 8; ++t) {
      const int c = w * 8 + t;               // B chunk 0..31
      int br = colBase + c * 8;
      if (br > VPAD - 8) br = VPAD - 8;      // tail clamp (see header comment)
      gload_lds16(wb + (size_t)(br + srow) * EMBED + k0 + skel,
                  &lB[c * 1024]);
    }
  };

  const int aBase = l31 * 128;               // + mi*32*128
  const int bBase = (wc + l31) * 128;        // + ni*32*128

#pragma unroll
  for (int kt = 0; kt < 4; ++kt) {
    stage(kt * 128);
    __syncthreads();                         // vmcnt(0)+lgkmcnt(0)+barrier
#pragma unroll
    for (int kk = 0; kk < 2; ++kk) {
      const int c0 = ((kk * 4 + h * 2) ^ kx) << 4;
      const int c1 = c0 ^ 16;
      i32x8 bq[2];
#pragma unroll
      for (int ni = 0; ni < 2; ++ni) {
        const uint8_t* bp = &lB[bBase + ni * 32 * 128];
        i32x4 lo = *(const i32x4*)(bp + c0);
        i32x4 hi = *(const i32x4*)(bp + c1);
        bq[ni] = __builtin_shufflevector(lo, hi, 0, 1, 2, 3, 4, 5, 6, 7);
      }
#pragma unroll
      for (int mi = 0; mi < 4; ++mi) {
        const uint8_t* ap = &lA[aBase + mi * 32 * 128];
        i32x4 lo = *(const i32x4*)(ap + c0);
        i32x4 hi = *(const i32x4*)(ap + c1);
        i32x8 af = __builtin_shufflevector(lo, hi, 0, 1, 2, 3, 4, 5, 6, 7);
        acc[mi][0] = __builtin_amdgcn_mfma_scale_f32_32x32x64_f8f6f4(
            af, bq[0], acc[mi][0], 0, 0, 0, 0x7F7F7F7F, 0, 0x7F7F7F7F);
        acc[mi][1] = __builtin_amdgcn_mfma_scale_f32_32x32x64_f8f6f4(
            af, bq[1], acc[mi][1], 0, 0, 0, 0x7F7F7F7F, 0, 0x7F7F7F7F);
      }
    }
    __syncthreads();                         // protect buffer reuse (single buf)
  }

  // ---- epilogue: s_row += sum_j exp(acc/16 + bias) ----
  // 32x32 C/D layout (m74/m101): col = lane&31, row = (reg&3)+8*(reg>>2)+4*h
  float bvl[2];
#pragma unroll
  for (int ni = 0; ni < 2; ++ni) {
    const int col = colBase + wc + ni * 32 + l31;
    bvl[ni] = (col < VOCAB) ? bias[col] * LOG2E : -1e30f;
  }

#pragma unroll
  for (int p = 0; p < 2; ++p) {            // p: 64-row half of the wave tile
    float sp[32];  // v = q*16 + reg, mi = p*2 + q
#pragma unroll
    for (int q = 0; q < 2; ++q)
#pragma unroll
      for (int r = 0; r < 16; ++r)
        sp[q * 16 + r] =
            exp2f(fmaf(acc[p * 2 + q][0][r], INV_WSCALE_L2E, bvl[0])) +
            exp2f(fmaf(acc[p * 2 + q][1][r], INV_WSCALE_L2E, bvl[1]));

    // stacking reduction over the 32 cols (xor 1..16 stays within the h-half);
    // ends with lane holding the full col-sum for value index v == (lane&31).
    float t1[16];
#pragma unroll
    for (int u = 0; u < 16; ++u) {
      float a = sp[2 * u]     + __shfl_xor(sp[2 * u],     1);
      float b = sp[2 * u + 1] + __shfl_xor(sp[2 * u + 1], 1);
      t1[u] = (l31 & 1) ? b : a;
    }
    float t2[8];
#pragma unroll
    for (int u = 0; u < 8; ++u) {
      float a = t1[2 * u]     + __shfl_xor(t1[2 * u],     2);
      float b = t1[2 * u + 1] + __shfl_xor(t1[2 * u + 1], 2);
      t2[u] = (l31 & 2) ? b : a;
    }
    float t3[4];
#pragma unroll
    for (int u = 0; u < 4; ++u) {
      float a = t2[2 * u]     + __shfl_xor(t2[2 * u],     4);
      float b = t2[2 * u + 1] + __shfl_xor(t2[2 * u + 1], 4);
      t3[u] = (l31 & 4) ? b : a;
    }
    float t4[2];
#pragma unroll
    for (int u = 0; u < 2; ++u) {
      float a = t3[2 * u]     + __shfl_xor(t3[2 * u],     8);
      float b = t3[2 * u + 1] + __shfl_xor(t3[2 * u + 1], 8);
      t4[u] = (l31 & 8) ? b : a;
    }
    {
      float a = t4[0] + __shfl_xor(t4[0], 16);
      float b = t4[1] + __shfl_xor(t4[1], 16);
      float ssum = (l31 & 16) ? b : a;
      const int v = l31;                 // q = v>>4, reg = v&15
      const int row = rowBase + p * 64 + (v >> 4) * 32 +
                      (v & 3) + 8 * ((v & 15) >> 2) + 4 * h;
      atomicAdd(&sg[row], ssum);
    }
  }
}

// ---- final: loss = log(V+1) - mean(py/s)  (q-term ~7e-10, dropped) ----
__global__ void finalize_kernel(const float* __restrict__ sg, const float* __restrict__ py,
                                float* __restrict__ out) {
  __shared__ float red[256];
  float a = 0.f;
  for (int i = threadIdx.x; i < NROWS; i += 256)
    a += py[i] / sg[i];
  red[threadIdx.x] = a;
  __syncthreads();
  for (int st = 128; st > 0; st >>= 1) {
    if (threadIdx.x < st) red[threadIdx.x] += red[threadIdx.x + st];
    __syncthreads();
  }
  if (threadIdx.x == 0)
    out[0] = logf((float)(VOCAB + 1)) - red[0] * (1.f / (float)NROWS);
}

extern "C" void kernel_launch(void* const* d_in, const int* in_sizes, int n_in,
                              void* d_out, int out_size, void* d_ws, size_t ws_size,
                              hipStream_t stream) {
  const float* x = (const float*)d_in[0];
  const int*   y = (const int*)d_in[1];
  const float* W = (const float*)d_in[2];
  const float* b = (const float*)d_in[3];

  char* ws = (char*)d_ws;
  uint8_t* xb = (uint8_t*)ws;                             // 4,194,304 B
  uint8_t* wb = (uint8_t*)(ws + 4194304);                 // 14,876,672 B
  float*   sg = (float*)(ws + 4194304 + 14876672);        // 32 KiB
  float*   py = sg + NROWS;                               // 32 KiB

  prep_kernel<<<11392, 256, 0, stream>>>(x, W, b, y, (int*)xb, (int*)wb, py, sg);
  gemm_stats_kernel<<<dim3(64, 114), 256, 0, stream>>>(xb, wb, b, sg);
  finalize_kernel<<<1, 256, 0, stream>>>(sg, py, (float*)d_out);
}